// Round 23
// baseline (186.511 us; speedup 1.0000x reference)
//
#include <hip/hip_runtime.h>

#define HID 64
#define INDIM 128
#define NBUCK 256          // bucket = dst >> 9  (512 nodes/bucket)
#define EBUF_PER 10240     // fixed ebuf region per bucket (raw, 22 sigma)
#define PAD_PER 14336      // fixed padded csr region per bucket
#define CHUNK 4096         // edges per binA block
#define RMASK 0x1FFFFu     // row-index mask (fault-safety for unconsumed loads)

typedef unsigned short ushort_t;
typedef unsigned int uint_t;
typedef float floatx2 __attribute__((ext_vector_type(2)));
typedef short bf16x8 __attribute__((ext_vector_type(8)));
typedef float f32x4 __attribute__((ext_vector_type(4)));

__device__ __forceinline__ float softplusf(float x) {
    return fmaxf(x, 0.f) + log1pf(expf(-fabsf(x)));
}
__device__ __forceinline__ ushort_t f2bf(float f) {
    union { float f; uint_t i; } c; c.f = f;
    uint_t u = c.i;
    u += 0x7FFFu + ((u >> 16) & 1u);
    return (ushort_t)(u >> 16);
}
__device__ __forceinline__ float dec_norm(uint_t x) {
    union { uint_t i; float f; } c; c.i = (x >> 17) << 16; return c.f;
}

// ===== K1: fused [binA (blocks 0..nbA) | MFMA gemm (rest)] =================
__global__ __launch_bounds__(256) void k_fused(const float* __restrict__ x,
                                               const float* __restrict__ W,
                                               const int* __restrict__ src,
                                               const int* __restrict__ dst,
                                               uint_t* __restrict__ Hq,
                                               int* __restrict__ bcur,
                                               int2* __restrict__ ebuf,
                                               int N, int E, int nbA) {
    __shared__ char lds[37888];
    int tid = threadIdx.x;

    if ((int)blockIdx.x < nbA) {
        // ---------------- binA ----------------
        int2* stage  = (int2*)lds;               // 32768
        int* lcnt    = (int*)(lds + 32768);
        int* binSt   = (int*)(lds + 33792);
        int* lofs    = (int*)(lds + 34816);
        int* gofs    = (int*)(lds + 35840);
        int* scn     = (int*)(lds + 36864);      // ..37888
        int base = blockIdx.x * CHUNK;

        lcnt[tid] = 0;
        __syncthreads();

        int sv[16], dv[16];
#pragma unroll
        for (int i = 0; i < 16; i++) {
            int e = base + i * 256 + tid;
            if (e < E) { sv[i] = src[e]; dv[i] = dst[e]; }
            else dv[i] = -1;
        }
#pragma unroll
        for (int i = 0; i < 16; i++)
            if (dv[i] >= 0) atomicAdd(&lcnt[dv[i] >> 9], 1);
        __syncthreads();

        scn[tid] = lcnt[tid];
        __syncthreads();
        for (int off = 1; off < NBUCK; off <<= 1) {
            int v = (tid >= off) ? scn[tid - off] : 0;
            __syncthreads();
            scn[tid] += v;
            __syncthreads();
        }
        binSt[tid] = scn[tid] - lcnt[tid];
        lofs[tid] = binSt[tid];
        __syncthreads();

#pragma unroll
        for (int i = 0; i < 16; i++) {
            if (dv[i] >= 0) {
                int b = dv[i] >> 9;
                int p = atomicAdd(&lofs[b], 1);
                stage[p] = make_int2(sv[i], dv[i]);
            }
        }
        __syncthreads();

        if (lcnt[tid] > 0)
            gofs[tid] = tid * EBUF_PER + atomicAdd(&bcur[tid], lcnt[tid]);
        __syncthreads();

        int total = (base + CHUNK <= E) ? CHUNK : (E > base ? E - base : 0);
        for (int idx = tid; idx < total; idx += 256) {
            int2 v = stage[idx];
            int b = v.y >> 9;
            ebuf[gofs[b] + (idx - binSt[b])] = v;
        }
    } else {
        // ------- MFMA gemm: 64 rows x 64 cols, bf16 in, fp8 out ------------
        ushort_t* Wt = (ushort_t*)lds;                 // [64][136] bf16 = 17408
        ushort_t* Xs = (ushort_t*)(lds + 17408);       // [64][136] bf16 = 17408
        float*    Cs = (float*)(lds + 17408);          // aliases Xs post-compute
        int row0 = ((int)blockIdx.x - nbA) * 64;

        const float4* W4 = (const float4*)W;
#pragma unroll
        for (int i = 0; i < 8; i++) {
            int idx4 = tid + 256 * i;                  // 2048 float4s
            float4 v = W4[idx4];
            int gidx = idx4 * 4;
            int k = gidx >> 6, c = gidx & 63;
            Wt[(c + 0) * 136 + k] = f2bf(v.x);
            Wt[(c + 1) * 136 + k] = f2bf(v.y);
            Wt[(c + 2) * 136 + k] = f2bf(v.z);
            Wt[(c + 3) * 136 + k] = f2bf(v.w);
        }
#pragma unroll
        for (int i = 0; i < 8; i++) {
            int idx4 = tid + 256 * i;                  // 2048 float4s
            int gidx = idx4 * 4;
            int r = gidx >> 7, k = gidx & 127;
            int row = row0 + r;
            float4 v = make_float4(0.f, 0.f, 0.f, 0.f);
            if (row < N) v = *(const float4*)(x + (size_t)row * INDIM + k);
            ushort4 o;
            o.x = f2bf(v.x); o.y = f2bf(v.y); o.z = f2bf(v.z); o.w = f2bf(v.w);
            *(ushort4*)(&Xs[r * 136 + k]) = o;
        }
        __syncthreads();

        int wv = tid >> 6, l = tid & 63;
        int lr = l & 15, kb = l >> 4;
        int arow = wv * 16 + lr;
        f32x4 acc0 = {0.f, 0.f, 0.f, 0.f};
        f32x4 acc1 = {0.f, 0.f, 0.f, 0.f};
        f32x4 acc2 = {0.f, 0.f, 0.f, 0.f};
        f32x4 acc3 = {0.f, 0.f, 0.f, 0.f};
#pragma unroll
        for (int ks = 0; ks < 4; ks++) {
            int k0 = ks * 32 + kb * 8;
            bf16x8 af = *(const bf16x8*)(&Xs[arow * 136 + k0]);
            bf16x8 b0 = *(const bf16x8*)(&Wt[(0 * 16 + lr) * 136 + k0]);
            bf16x8 b1 = *(const bf16x8*)(&Wt[(1 * 16 + lr) * 136 + k0]);
            bf16x8 b2 = *(const bf16x8*)(&Wt[(2 * 16 + lr) * 136 + k0]);
            bf16x8 b3 = *(const bf16x8*)(&Wt[(3 * 16 + lr) * 136 + k0]);
            acc0 = __builtin_amdgcn_mfma_f32_16x16x32_bf16(af, b0, acc0, 0, 0, 0);
            acc1 = __builtin_amdgcn_mfma_f32_16x16x32_bf16(af, b1, acc1, 0, 0, 0);
            acc2 = __builtin_amdgcn_mfma_f32_16x16x32_bf16(af, b2, acc2, 0, 0, 0);
            acc3 = __builtin_amdgcn_mfma_f32_16x16x32_bf16(af, b3, acc3, 0, 0, 0);
        }
        __syncthreads();
#pragma unroll
        for (int j = 0; j < 4; j++) {
            int crow = wv * 16 + (l >> 4) * 4 + j;
            Cs[crow * 64 + 0 * 16 + lr] = acc0[j];
            Cs[crow * 64 + 1 * 16 + lr] = acc1[j];
            Cs[crow * 64 + 2 * 16 + lr] = acc2[j];
            Cs[crow * 64 + 3 * 16 + lr] = acc3[j];
        }
        __syncthreads();
#pragma unroll
        for (int i = 0; i < 4; i++) {
            int idx = tid + 256 * i;                   // 1024 u32 outputs
            int r = idx >> 4, c4 = idx & 15;
            int row = row0 + r;
            if (row < N) {
                float v0 = Cs[r * 64 + c4 * 4 + 0];
                float v1 = Cs[r * 64 + c4 * 4 + 1];
                float v2 = Cs[r * 64 + c4 * 4 + 2];
                float v3 = Cs[r * 64 + c4 * 4 + 3];
                uint_t u = 0;
                u = __builtin_amdgcn_cvt_pk_fp8_f32(v0, v1, u, false);
                u = __builtin_amdgcn_cvt_pk_fp8_f32(v2, v3, u, true);
                Hq[(size_t)row * 16 + c4] = u;
            }
        }
    }
}

// ===== K2: fused [binB1 (blocks 0..nbB) | HC build (rest)] =================
// binB1: per-bucket degrees -> packed padded rowptr, dinv.
// HC: HC[n] = { Hq[n] | Hq[perm[n]] } (16+16 u32).
__global__ __launch_bounds__(256) void k_binB1hc(const int2* __restrict__ ebuf,
                                                 const int* __restrict__ bcur,
                                                 int* __restrict__ rowptr,
                                                 float* __restrict__ dinvg,
                                                 const uint_t* __restrict__ Hq,
                                                 const int* __restrict__ perm,
                                                 uint_t* __restrict__ HC,
                                                 int N, int nbB) {
    int tid = threadIdx.x;
    if ((int)blockIdx.x >= nbB) {
        int g = ((int)blockIdx.x - nbB) * 256 + tid;   // over N*16
        if (g < N * 16) {
            int n = g >> 4, sub = g & 15;
            HC[(size_t)n * 32 + sub] = Hq[(size_t)n * 16 + sub];
            HC[(size_t)n * 32 + 16 + sub] = Hq[(size_t)perm[n] * 16 + sub];
        }
        return;
    }
    __shared__ int sc[256];
    __shared__ int ldeg[512];
    int b = blockIdx.x;

    ldeg[tid] = 0;
    ldeg[tid + 256] = 0;
    __syncthreads();

    int start = b * EBUF_PER;
    int cb = bcur[b];
    for (int i = start + tid; i < start + cb; i += 256)
        atomicAdd(&ldeg[ebuf[i].y & 511], 1);
    __syncthreads();

    int d0 = ldeg[2 * tid], d1 = ldeg[2 * tid + 1];
    int p0 = (d0 + 7) & ~7, p1 = (d1 + 7) & ~7;
    int s2 = p0 + p1;
    sc[tid] = s2;
    __syncthreads();
    for (int off = 1; off < 256; off <<= 1) {
        int v = (tid >= off) ? sc[tid - off] : 0;
        __syncthreads();
        sc[tid] += v;
        __syncthreads();
    }
    int ex = sc[tid] - s2;
    int n0 = (b << 9) + 2 * tid, n1 = n0 + 1;
    int prow0 = b * PAD_PER + ex;
    int prow1 = prow0 + p0;
    if (n0 < N) { rowptr[n0] = prow0 | ((p0 >> 3) << 23); dinvg[n0] = rsqrtf((float)(d0 + 1)); }
    if (n1 < N) { rowptr[n1] = prow1 | ((p1 >> 3) << 23); dinvg[n1] = rsqrtf((float)(d1 + 1)); }
}

// ===== K3: binB2 — placement: csrS[j] = u32 { s | norm15<<17 } + pad fill ==
__global__ __launch_bounds__(256) void k_binB2(const int2* __restrict__ ebuf,
                                               const int* __restrict__ bcur,
                                               const int* __restrict__ rowptr,
                                               const float* __restrict__ dinvg,
                                               uint_t* __restrict__ csrS, int N) {
    __shared__ int lcur[512];
    __shared__ float ldinv[512];
    int tid = threadIdx.x;
    int b = blockIdx.x;
    int nodeBase = b << 9;
    for (int i = tid; i < 512; i += 256) {
        int n = nodeBase + i;
        lcur[i] = (n < N) ? (rowptr[n] & 0x7FFFFF) : 0;
        ldinv[i] = (n < N) ? dinvg[n] : 0.f;
    }
    __syncthreads();

    int start = b * EBUF_PER;
    int cb = bcur[b];
    for (int i = start + tid; i < start + cb; i += 256) {
        int2 v = ebuf[i];
        int s = v.x, dl = v.y & 511;
        int j = atomicAdd(&lcur[dl], 1);
        float nm = dinvg[s] * ldinv[dl];
        union { float f; uint_t u; } cu; cu.f = nm;
        uint_t nb = (cu.u >> 16) & 0x7FFFu;
        csrS[j] = (uint_t)s | (nb << 17);
    }
    __syncthreads();

    for (int i = tid; i < 512; i += 256) {
        int n = nodeBase + i;
        if (n < N) {
            uint_t r = (uint_t)rowptr[n];
            int e = (int)(r & 0x7FFFFF) + 8 * (int)(r >> 23);
            for (int j = lcur[i]; j < e; j++) csrS[j] = 0u;
        }
    }
}

// ===== K4: gather — HC records, nontemporal csr stream, branchless =========
__global__ __launch_bounds__(256) void k_gather(const uint_t* __restrict__ HC,
                                                const int* __restrict__ rowptr,
                                                const uint_t* __restrict__ csrS,
                                                const float* __restrict__ dinv,
                                                const float* __restrict__ b,
                                                const float* __restrict__ a,
                                                uint_t* __restrict__ posq,
                                                uint_t* __restrict__ negq,
                                                float* __restrict__ sumvec, int N) {
    int tid = threadIdx.x;
    int lane = tid & 63;
    int slot = lane >> 4;
    int sub = lane & 15;
    int isneg = slot & 1;
    int pair = slot >> 1;
    int hoff = isneg * 16 + sub;
    int wid = (blockIdx.x * 256 + tid) >> 6;
    int nw = gridDim.x * 4;
    float4 b4 = ((const float4*)b)[sub];
    float4 a4 = ((const float4*)a)[sub];
    float s0 = 0.f, s1 = 0.f, s2 = 0.f, s3 = 0.f;

    for (int n = wid; n < N; n += nw) {
        float dv = dinv[n];
        float w2 = dv * dv;
        uint_t r = (uint_t)rowptr[n];
        int beg = (int)(r & 0x7FFFFF);
        int iters = (int)(r >> 23);
        float a0 = 0.f, a1 = 0.f, a2 = 0.f, a3 = 0.f;

        int base0 = beg + pair;
        uint_t cA0 = __builtin_nontemporal_load(&csrS[base0]);
        uint_t cA1 = __builtin_nontemporal_load(&csrS[base0 + 2]);
        uint_t cA2 = __builtin_nontemporal_load(&csrS[base0 + 4]);
        uint_t cA3 = __builtin_nontemporal_load(&csrS[base0 + 6]);
        uint_t cB0 = __builtin_nontemporal_load(&csrS[base0 + 8]);
        uint_t cB1 = __builtin_nontemporal_load(&csrS[base0 + 10]);
        uint_t cB2 = __builtin_nontemporal_load(&csrS[base0 + 12]);
        uint_t cB3 = __builtin_nontemporal_load(&csrS[base0 + 14]);
        uint_t uc0 = HC[(size_t)(cA0 & RMASK) * 32 + hoff];
        uint_t uc1 = HC[(size_t)(cA1 & RMASK) * 32 + hoff];
        uint_t uc2 = HC[(size_t)(cA2 & RMASK) * 32 + hoff];
        uint_t uc3 = HC[(size_t)(cA3 & RMASK) * 32 + hoff];

        for (int it = 0; it < iters; it++) {
            int gbase = base0 + (it + 2) * 8;
            uint_t cC0 = __builtin_nontemporal_load(&csrS[gbase]);
            uint_t cC1 = __builtin_nontemporal_load(&csrS[gbase + 2]);
            uint_t cC2 = __builtin_nontemporal_load(&csrS[gbase + 4]);
            uint_t cC3 = __builtin_nontemporal_load(&csrS[gbase + 6]);
            uint_t un0 = HC[(size_t)(cB0 & RMASK) * 32 + hoff];
            uint_t un1 = HC[(size_t)(cB1 & RMASK) * 32 + hoff];
            uint_t un2 = HC[(size_t)(cB2 & RMASK) * 32 + hoff];
            uint_t un3 = HC[(size_t)(cB3 & RMASK) * 32 + hoff];
            float mA0 = dec_norm(cA0);
            float mA1 = dec_norm(cA1);
            float mA2 = dec_norm(cA2);
            float mA3 = dec_norm(cA3);
            floatx2 lo, hi;
            lo = __builtin_amdgcn_cvt_pk_f32_fp8(uc0, false);
            hi = __builtin_amdgcn_cvt_pk_f32_fp8(uc0, true);
            a0 = fmaf(lo.x, mA0, a0); a1 = fmaf(lo.y, mA0, a1);
            a2 = fmaf(hi.x, mA0, a2); a3 = fmaf(hi.y, mA0, a3);
            lo = __builtin_amdgcn_cvt_pk_f32_fp8(uc1, false);
            hi = __builtin_amdgcn_cvt_pk_f32_fp8(uc1, true);
            a0 = fmaf(lo.x, mA1, a0); a1 = fmaf(lo.y, mA1, a1);
            a2 = fmaf(hi.x, mA1, a2); a3 = fmaf(hi.y, mA1, a3);
            lo = __builtin_amdgcn_cvt_pk_f32_fp8(uc2, false);
            hi = __builtin_amdgcn_cvt_pk_f32_fp8(uc2, true);
            a0 = fmaf(lo.x, mA2, a0); a1 = fmaf(lo.y, mA2, a1);
            a2 = fmaf(hi.x, mA2, a2); a3 = fmaf(hi.y, mA2, a3);
            lo = __builtin_amdgcn_cvt_pk_f32_fp8(uc3, false);
            hi = __builtin_amdgcn_cvt_pk_f32_fp8(uc3, true);
            a0 = fmaf(lo.x, mA3, a0); a1 = fmaf(lo.y, mA3, a1);
            a2 = fmaf(hi.x, mA3, a2); a3 = fmaf(hi.y, mA3, a3);
            cA0 = cB0; cA1 = cB1; cA2 = cB2; cA3 = cB3;
            cB0 = cC0; cB1 = cC1; cB2 = cC2; cB3 = cC3;
            uc0 = un0; uc1 = un1; uc2 = un2; uc3 = un3;
        }
        a0 += __shfl_xor(a0, 32);
        a1 += __shfl_xor(a1, 32);
        a2 += __shfl_xor(a2, 32);
        a3 += __shfl_xor(a3, 32);
        uint_t us = HC[(size_t)n * 32 + hoff];
        floatx2 slo = __builtin_amdgcn_cvt_pk_f32_fp8(us, false);
        floatx2 shi = __builtin_amdgcn_cvt_pk_f32_fp8(us, true);
        float v0 = fmaf(slo.x, w2, a0) + b4.x;
        float v1 = fmaf(slo.y, w2, a1) + b4.y;
        float v2 = fmaf(shi.x, w2, a2) + b4.z;
        float v3 = fmaf(shi.y, w2, a3) + b4.w;
        v0 = v0 > 0.f ? v0 : v0 * a4.x;
        v1 = v1 > 0.f ? v1 : v1 * a4.y;
        v2 = v2 > 0.f ? v2 : v2 * a4.z;
        v3 = v3 > 0.f ? v3 : v3 * a4.w;
        if (lane < 32) {
            uint_t pk = 0;
            pk = __builtin_amdgcn_cvt_pk_fp8_f32(v0, v1, pk, false);
            pk = __builtin_amdgcn_cvt_pk_fp8_f32(v2, v3, pk, true);
            uint_t* outp = isneg ? negq : posq;
            outp[(size_t)n * 16 + sub] = pk;
            if (!isneg) { s0 += v0; s1 += v1; s2 += v2; s3 += v3; }
        }
    }

    __shared__ float red[4][64];
    int w = tid >> 6;
    if (slot == 0) {
        red[w][sub * 4 + 0] = s0;
        red[w][sub * 4 + 1] = s1;
        red[w][sub * 4 + 2] = s2;
        red[w][sub * 4 + 3] = s3;
    }
    __syncthreads();
    if (tid < 64) {
        float s = red[0][tid] + red[1][tid] + red[2][tid] + red[3][tid];
        atomicAdd(&sumvec[tid], s);
    }
}

// ===== K5: loss — fp8 pos/neg, 2 nodes/wave-iter, disc fused, final ========
__global__ __launch_bounds__(256) void k_loss(const uint_t* __restrict__ posq,
                                              const uint_t* __restrict__ negq,
                                              float* __restrict__ smallb,
                                              const float* __restrict__ Wd,
                                              float* __restrict__ out, int N) {
    __shared__ float summ[64];
    __shared__ float svecS[64];
    __shared__ float redL[4][4];
    int tid = threadIdx.x;
    float* sumvec = smallb;
    float* lossAcc = smallb + 128;
    int* done = (int*)(smallb + 129);

    if (tid < 64) summ[tid] = 1.f / (1.f + expf(-sumvec[tid] / (float)N));
    __syncthreads();
    if (tid < 64) {
        float s = 0.f;
#pragma unroll
        for (int j = 0; j < 64; j++) s += Wd[tid * 64 + j] * summ[j];
        svecS[tid] = s;
    }
    __syncthreads();

    int lane = tid & 63;
    int slot = lane >> 4;
    int sub = lane & 15;
    int isneg = slot & 1;
    int pair = slot >> 1;
    int w = tid >> 6;
    float4 sv = ((const float4*)svecS)[sub];
    const uint_t* Pb = isneg ? negq : posq;
    float l = 0.f;
    int wid = (blockIdx.x * 256 + tid) >> 6;
    int nw = gridDim.x * 4;
    for (int g = wid; 2 * g < N; g += nw) {
        int row = 2 * g + pair;
        bool valid = row < N;
        uint_t u = valid ? Pb[(size_t)row * 16 + sub] : 0u;
        floatx2 lo = __builtin_amdgcn_cvt_pk_f32_fp8(u, false);
        floatx2 hi = __builtin_amdgcn_cvt_pk_f32_fp8(u, true);
        float p = lo.x * sv.x + lo.y * sv.y + hi.x * sv.z + hi.y * sv.w;
        p += __shfl_xor(p, 1);
        p += __shfl_xor(p, 2);
        p += __shfl_xor(p, 4);
        p += __shfl_xor(p, 8);
        if (sub == 0 && valid) l += isneg ? softplusf(p) : softplusf(-p);
    }
    if (sub == 0) redL[w][slot] = l;
    __syncthreads();
    if (tid == 0) {
        float t = 0.f;
#pragma unroll
        for (int i = 0; i < 4; i++)
#pragma unroll
            for (int j = 0; j < 4; j++) t += redL[i][j];
        atomicAdd(&lossAcc[0], t);
        __threadfence();
        int old = atomicAdd(done, 1);
        if (old == (int)gridDim.x - 1) {
            float tot = atomicAdd(&lossAcc[0], 0.f);
            out[0] = tot / (float)N;
        }
    }
}

extern "C" void kernel_launch(void* const* d_in, const int* in_sizes, int n_in,
                              void* d_out, int out_size, void* d_ws, size_t ws_size,
                              hipStream_t stream) {
    const float* x      = (const float*)d_in[0];
    const float* W_gcn  = (const float*)d_in[1];
    const float* b_gcn  = (const float*)d_in[2];
    const float* prelu_a= (const float*)d_in[3];
    const float* W_disc = (const float*)d_in[4];
    const int*   eidx   = (const int*)d_in[5];
    const int*   perm   = (const int*)d_in[6];

    int N = in_sizes[0] / INDIM;      // 100000
    int E = in_sizes[5] / 2;          // 1600000
    const int* src = eidx;
    const int* dst = eidx + E;

    char* base = (char*)d_ws;
    size_t off = 0;
    auto alloc = [&](size_t bytes) { size_t o = off; off = (off + bytes + 255) & ~(size_t)255; return o; };
    uint_t*   Hq    = (uint_t*)  (base + alloc((size_t)N * HID));              // fp8: 6.4 MB
    uint_t*   HC    = (uint_t*)  (base + alloc(((size_t)0x20000 * 32) * 4));   // 16.8 MB
    uint_t*   posq  = (uint_t*)  (base + alloc((size_t)N * HID));              // fp8
    uint_t*   negq  = (uint_t*)  (base + alloc((size_t)N * HID));              // fp8
    uint_t*   csrS  = (uint_t*)  (base + alloc(((size_t)NBUCK * PAD_PER + 64) * 4));
    int2*     ebuf  = (int2*)   (base + alloc((size_t)NBUCK * EBUF_PER * 8));
    int*      rowptr= (int*)    (base + alloc(((size_t)N + 1) * 4));
    float*    dinv  = (float*)  (base + alloc((size_t)N * 4));
    size_t zOff = alloc(NBUCK * 4 + 132 * 4);
    int*      bcur  = (int*)(base + zOff);
    float*    smallb= (float*)(base + zOff + NBUCK * 4);
    float* sumvec = smallb;

    int nbA = (E + CHUNK - 1) / CHUNK;    // 391
    int nbG = (N + 63) / 64;              // 1563
    int nbB = (N + 511) / 512;            // 196
    int nbH = (N * 16 + 255) / 256;       // 6250

    hipMemsetAsync(bcur, 0, NBUCK * 4 + 132 * 4, stream);
    k_fused<<<nbA + nbG, 256, 0, stream>>>(x, W_gcn, src, dst, Hq, bcur, ebuf, N, E, nbA);
    k_binB1hc<<<nbB + nbH, 256, 0, stream>>>(ebuf, bcur, rowptr, dinv, Hq, perm, HC, N, nbB);
    k_binB2<<<nbB, 256, 0, stream>>>(ebuf, bcur, rowptr, dinv, csrS, N);
    k_gather<<<2048, 256, 0, stream>>>(HC, rowptr, csrS, dinv,
                                       b_gcn, prelu_a, posq, negq, sumvec, N);
    k_loss<<<512, 256, 0, stream>>>(posq, negq, smallb, W_disc, (float*)d_out, N);
}

// Round 24
// 179.565 us; speedup vs baseline: 1.0387x; 1.0387x over previous
//
#include <hip/hip_runtime.h>

#define HID 64
#define INDIM 128
#define NBUCK 256          // bucket = dst >> 9  (512 nodes/bucket)
#define EBUF_PER 10240     // fixed ebuf region per bucket (raw, 22 sigma)
#define PAD_PER 14336      // fixed padded csr region per bucket
#define CHUNK 4096         // edges per binA block
#define RMASK 0x1FFFFu     // row-index mask (fault-safety for unconsumed loads)

typedef unsigned short ushort_t;
typedef unsigned int uint_t;
typedef float floatx2 __attribute__((ext_vector_type(2)));
typedef short bf16x8 __attribute__((ext_vector_type(8)));
typedef float f32x4 __attribute__((ext_vector_type(4)));

__device__ __forceinline__ float softplusf(float x) {
    return fmaxf(x, 0.f) + log1pf(expf(-fabsf(x)));
}
__device__ __forceinline__ ushort_t f2bf(float f) {
    union { float f; uint_t i; } c; c.f = f;
    uint_t u = c.i;
    u += 0x7FFFu + ((u >> 16) & 1u);
    return (ushort_t)(u >> 16);
}
__device__ __forceinline__ float dec_norm(uint_t x) {
    union { uint_t i; float f; } c; c.i = (x >> 17) << 16; return c.f;
}

// ===== K1: fused [binA (blocks 0..nbA) | MFMA gemm (rest)] =================
__global__ __launch_bounds__(256) void k_fused(const float* __restrict__ x,
                                               const float* __restrict__ W,
                                               const int* __restrict__ src,
                                               const int* __restrict__ dst,
                                               uint_t* __restrict__ Hq,
                                               int* __restrict__ bcur,
                                               int2* __restrict__ ebuf,
                                               int N, int E, int nbA) {
    __shared__ char lds[37888];
    int tid = threadIdx.x;

    if ((int)blockIdx.x < nbA) {
        // ---------------- binA ----------------
        int2* stage  = (int2*)lds;               // 32768
        int* lcnt    = (int*)(lds + 32768);
        int* binSt   = (int*)(lds + 33792);
        int* lofs    = (int*)(lds + 34816);
        int* gofs    = (int*)(lds + 35840);
        int* scn     = (int*)(lds + 36864);      // ..37888
        int base = blockIdx.x * CHUNK;

        lcnt[tid] = 0;
        __syncthreads();

        int sv[16], dv[16];
#pragma unroll
        for (int i = 0; i < 16; i++) {
            int e = base + i * 256 + tid;
            if (e < E) { sv[i] = src[e]; dv[i] = dst[e]; }
            else dv[i] = -1;
        }
#pragma unroll
        for (int i = 0; i < 16; i++)
            if (dv[i] >= 0) atomicAdd(&lcnt[dv[i] >> 9], 1);
        __syncthreads();

        scn[tid] = lcnt[tid];
        __syncthreads();
        for (int off = 1; off < NBUCK; off <<= 1) {
            int v = (tid >= off) ? scn[tid - off] : 0;
            __syncthreads();
            scn[tid] += v;
            __syncthreads();
        }
        binSt[tid] = scn[tid] - lcnt[tid];
        lofs[tid] = binSt[tid];
        __syncthreads();

#pragma unroll
        for (int i = 0; i < 16; i++) {
            if (dv[i] >= 0) {
                int b = dv[i] >> 9;
                int p = atomicAdd(&lofs[b], 1);
                stage[p] = make_int2(sv[i], dv[i]);
            }
        }
        __syncthreads();

        if (lcnt[tid] > 0)
            gofs[tid] = tid * EBUF_PER + atomicAdd(&bcur[tid], lcnt[tid]);
        __syncthreads();

        int total = (base + CHUNK <= E) ? CHUNK : (E > base ? E - base : 0);
        for (int idx = tid; idx < total; idx += 256) {
            int2 v = stage[idx];
            int b = v.y >> 9;
            ebuf[gofs[b] + (idx - binSt[b])] = v;
        }
    } else {
        // ------- MFMA gemm: 64 rows x 64 cols, bf16 in, fp8 out ------------
        ushort_t* Wt = (ushort_t*)lds;                 // [64][136] bf16 = 17408
        ushort_t* Xs = (ushort_t*)(lds + 17408);       // [64][136] bf16 = 17408
        float*    Cs = (float*)(lds + 17408);          // aliases Xs post-compute
        int row0 = ((int)blockIdx.x - nbA) * 64;

        const float4* W4 = (const float4*)W;
#pragma unroll
        for (int i = 0; i < 8; i++) {
            int idx4 = tid + 256 * i;                  // 2048 float4s
            float4 v = W4[idx4];
            int gidx = idx4 * 4;
            int k = gidx >> 6, c = gidx & 63;
            Wt[(c + 0) * 136 + k] = f2bf(v.x);
            Wt[(c + 1) * 136 + k] = f2bf(v.y);
            Wt[(c + 2) * 136 + k] = f2bf(v.z);
            Wt[(c + 3) * 136 + k] = f2bf(v.w);
        }
#pragma unroll
        for (int i = 0; i < 8; i++) {
            int idx4 = tid + 256 * i;                  // 2048 float4s
            int gidx = idx4 * 4;
            int r = gidx >> 7, k = gidx & 127;
            int row = row0 + r;
            float4 v = make_float4(0.f, 0.f, 0.f, 0.f);
            if (row < N) v = *(const float4*)(x + (size_t)row * INDIM + k);
            ushort4 o;
            o.x = f2bf(v.x); o.y = f2bf(v.y); o.z = f2bf(v.z); o.w = f2bf(v.w);
            *(ushort4*)(&Xs[r * 136 + k]) = o;
        }
        __syncthreads();

        int wv = tid >> 6, l = tid & 63;
        int lr = l & 15, kb = l >> 4;
        int arow = wv * 16 + lr;
        f32x4 acc0 = {0.f, 0.f, 0.f, 0.f};
        f32x4 acc1 = {0.f, 0.f, 0.f, 0.f};
        f32x4 acc2 = {0.f, 0.f, 0.f, 0.f};
        f32x4 acc3 = {0.f, 0.f, 0.f, 0.f};
#pragma unroll
        for (int ks = 0; ks < 4; ks++) {
            int k0 = ks * 32 + kb * 8;
            bf16x8 af = *(const bf16x8*)(&Xs[arow * 136 + k0]);
            bf16x8 b0 = *(const bf16x8*)(&Wt[(0 * 16 + lr) * 136 + k0]);
            bf16x8 b1 = *(const bf16x8*)(&Wt[(1 * 16 + lr) * 136 + k0]);
            bf16x8 b2 = *(const bf16x8*)(&Wt[(2 * 16 + lr) * 136 + k0]);
            bf16x8 b3 = *(const bf16x8*)(&Wt[(3 * 16 + lr) * 136 + k0]);
            acc0 = __builtin_amdgcn_mfma_f32_16x16x32_bf16(af, b0, acc0, 0, 0, 0);
            acc1 = __builtin_amdgcn_mfma_f32_16x16x32_bf16(af, b1, acc1, 0, 0, 0);
            acc2 = __builtin_amdgcn_mfma_f32_16x16x32_bf16(af, b2, acc2, 0, 0, 0);
            acc3 = __builtin_amdgcn_mfma_f32_16x16x32_bf16(af, b3, acc3, 0, 0, 0);
        }
        __syncthreads();
#pragma unroll
        for (int j = 0; j < 4; j++) {
            int crow = wv * 16 + (l >> 4) * 4 + j;
            Cs[crow * 64 + 0 * 16 + lr] = acc0[j];
            Cs[crow * 64 + 1 * 16 + lr] = acc1[j];
            Cs[crow * 64 + 2 * 16 + lr] = acc2[j];
            Cs[crow * 64 + 3 * 16 + lr] = acc3[j];
        }
        __syncthreads();
#pragma unroll
        for (int i = 0; i < 4; i++) {
            int idx = tid + 256 * i;                   // 1024 u32 outputs
            int r = idx >> 4, c4 = idx & 15;
            int row = row0 + r;
            if (row < N) {
                float v0 = Cs[r * 64 + c4 * 4 + 0];
                float v1 = Cs[r * 64 + c4 * 4 + 1];
                float v2 = Cs[r * 64 + c4 * 4 + 2];
                float v3 = Cs[r * 64 + c4 * 4 + 3];
                uint_t u = 0;
                u = __builtin_amdgcn_cvt_pk_fp8_f32(v0, v1, u, false);
                u = __builtin_amdgcn_cvt_pk_fp8_f32(v2, v3, u, true);
                Hq[(size_t)row * 16 + c4] = u;
            }
        }
    }
}

// ===== K2: fused [binB1 (blocks 0..nbB) | HC build (rest)] =================
__global__ __launch_bounds__(256) void k_binB1hc(const int2* __restrict__ ebuf,
                                                 const int* __restrict__ bcur,
                                                 int* __restrict__ rowptr,
                                                 float* __restrict__ dinvg,
                                                 const uint_t* __restrict__ Hq,
                                                 const int* __restrict__ perm,
                                                 uint_t* __restrict__ HC,
                                                 int N, int nbB) {
    int tid = threadIdx.x;
    if ((int)blockIdx.x >= nbB) {
        int g = ((int)blockIdx.x - nbB) * 256 + tid;   // over N*16
        if (g < N * 16) {
            int n = g >> 4, sub = g & 15;
            HC[(size_t)n * 32 + sub] = Hq[(size_t)n * 16 + sub];
            HC[(size_t)n * 32 + 16 + sub] = Hq[(size_t)perm[n] * 16 + sub];
        }
        return;
    }
    __shared__ int sc[256];
    __shared__ int ldeg[512];
    int b = blockIdx.x;

    ldeg[tid] = 0;
    ldeg[tid + 256] = 0;
    __syncthreads();

    int start = b * EBUF_PER;
    int cb = bcur[b];
    for (int i = start + tid; i < start + cb; i += 256)
        atomicAdd(&ldeg[ebuf[i].y & 511], 1);
    __syncthreads();

    int d0 = ldeg[2 * tid], d1 = ldeg[2 * tid + 1];
    int p0 = (d0 + 7) & ~7, p1 = (d1 + 7) & ~7;
    int s2 = p0 + p1;
    sc[tid] = s2;
    __syncthreads();
    for (int off = 1; off < 256; off <<= 1) {
        int v = (tid >= off) ? sc[tid - off] : 0;
        __syncthreads();
        sc[tid] += v;
        __syncthreads();
    }
    int ex = sc[tid] - s2;
    int n0 = (b << 9) + 2 * tid, n1 = n0 + 1;
    int prow0 = b * PAD_PER + ex;
    int prow1 = prow0 + p0;
    if (n0 < N) { rowptr[n0] = prow0 | ((p0 >> 3) << 23); dinvg[n0] = rsqrtf((float)(d0 + 1)); }
    if (n1 < N) { rowptr[n1] = prow1 | ((p1 >> 3) << 23); dinvg[n1] = rsqrtf((float)(d1 + 1)); }
}

// ===== K3: binB2 — placement: csrS[j] = u32 { s | norm15<<17 } + pad fill ==
__global__ __launch_bounds__(256) void k_binB2(const int2* __restrict__ ebuf,
                                               const int* __restrict__ bcur,
                                               const int* __restrict__ rowptr,
                                               const float* __restrict__ dinvg,
                                               uint_t* __restrict__ csrS, int N) {
    __shared__ int lcur[512];
    __shared__ float ldinv[512];
    int tid = threadIdx.x;
    int b = blockIdx.x;
    int nodeBase = b << 9;
    for (int i = tid; i < 512; i += 256) {
        int n = nodeBase + i;
        lcur[i] = (n < N) ? (rowptr[n] & 0x7FFFFF) : 0;
        ldinv[i] = (n < N) ? dinvg[n] : 0.f;
    }
    __syncthreads();

    int start = b * EBUF_PER;
    int cb = bcur[b];
    for (int i = start + tid; i < start + cb; i += 256) {
        int2 v = ebuf[i];
        int s = v.x, dl = v.y & 511;
        int j = atomicAdd(&lcur[dl], 1);
        float nm = dinvg[s] * ldinv[dl];
        union { float f; uint_t u; } cu; cu.f = nm;
        uint_t nb = (cu.u >> 16) & 0x7FFFu;
        csrS[j] = (uint_t)s | (nb << 17);
    }
    __syncthreads();

    for (int i = tid; i < 512; i += 256) {
        int n = nodeBase + i;
        if (n < N) {
            uint_t r = (uint_t)rowptr[n];
            int e = (int)(r & 0x7FFFFF) + 8 * (int)(r >> 23);
            for (int j = lcur[i]; j < e; j++) csrS[j] = 0u;
        }
    }
}

// ===== K4: gather — HC records (128 B/edge), branchless, plain loads =======
__global__ __launch_bounds__(256) void k_gather(const uint_t* __restrict__ HC,
                                                const int* __restrict__ rowptr,
                                                const uint_t* __restrict__ csrS,
                                                const float* __restrict__ dinv,
                                                const float* __restrict__ b,
                                                const float* __restrict__ a,
                                                uint_t* __restrict__ posq,
                                                uint_t* __restrict__ negq,
                                                float* __restrict__ sumvec, int N) {
    int tid = threadIdx.x;
    int lane = tid & 63;
    int slot = lane >> 4;
    int sub = lane & 15;
    int isneg = slot & 1;
    int pair = slot >> 1;
    int hoff = isneg * 16 + sub;
    int wid = (blockIdx.x * 256 + tid) >> 6;
    int nw = gridDim.x * 4;
    float4 b4 = ((const float4*)b)[sub];
    float4 a4 = ((const float4*)a)[sub];
    float s0 = 0.f, s1 = 0.f, s2 = 0.f, s3 = 0.f;

    for (int n = wid; n < N; n += nw) {
        float dv = dinv[n];
        float w2 = dv * dv;
        uint_t r = (uint_t)rowptr[n];
        int beg = (int)(r & 0x7FFFFF);
        int iters = (int)(r >> 23);
        float a0 = 0.f, a1 = 0.f, a2 = 0.f, a3 = 0.f;

        int base0 = beg + pair;
        uint_t cA0 = csrS[base0];
        uint_t cA1 = csrS[base0 + 2];
        uint_t cA2 = csrS[base0 + 4];
        uint_t cA3 = csrS[base0 + 6];
        uint_t cB0 = csrS[base0 + 8];
        uint_t cB1 = csrS[base0 + 10];
        uint_t cB2 = csrS[base0 + 12];
        uint_t cB3 = csrS[base0 + 14];
        uint_t uc0 = HC[(size_t)(cA0 & RMASK) * 32 + hoff];
        uint_t uc1 = HC[(size_t)(cA1 & RMASK) * 32 + hoff];
        uint_t uc2 = HC[(size_t)(cA2 & RMASK) * 32 + hoff];
        uint_t uc3 = HC[(size_t)(cA3 & RMASK) * 32 + hoff];

        for (int it = 0; it < iters; it++) {
            int gbase = base0 + (it + 2) * 8;
            uint_t cC0 = csrS[gbase];
            uint_t cC1 = csrS[gbase + 2];
            uint_t cC2 = csrS[gbase + 4];
            uint_t cC3 = csrS[gbase + 6];
            uint_t un0 = HC[(size_t)(cB0 & RMASK) * 32 + hoff];
            uint_t un1 = HC[(size_t)(cB1 & RMASK) * 32 + hoff];
            uint_t un2 = HC[(size_t)(cB2 & RMASK) * 32 + hoff];
            uint_t un3 = HC[(size_t)(cB3 & RMASK) * 32 + hoff];
            float mA0 = dec_norm(cA0);
            float mA1 = dec_norm(cA1);
            float mA2 = dec_norm(cA2);
            float mA3 = dec_norm(cA3);
            floatx2 lo, hi;
            lo = __builtin_amdgcn_cvt_pk_f32_fp8(uc0, false);
            hi = __builtin_amdgcn_cvt_pk_f32_fp8(uc0, true);
            a0 = fmaf(lo.x, mA0, a0); a1 = fmaf(lo.y, mA0, a1);
            a2 = fmaf(hi.x, mA0, a2); a3 = fmaf(hi.y, mA0, a3);
            lo = __builtin_amdgcn_cvt_pk_f32_fp8(uc1, false);
            hi = __builtin_amdgcn_cvt_pk_f32_fp8(uc1, true);
            a0 = fmaf(lo.x, mA1, a0); a1 = fmaf(lo.y, mA1, a1);
            a2 = fmaf(hi.x, mA1, a2); a3 = fmaf(hi.y, mA1, a3);
            lo = __builtin_amdgcn_cvt_pk_f32_fp8(uc2, false);
            hi = __builtin_amdgcn_cvt_pk_f32_fp8(uc2, true);
            a0 = fmaf(lo.x, mA2, a0); a1 = fmaf(lo.y, mA2, a1);
            a2 = fmaf(hi.x, mA2, a2); a3 = fmaf(hi.y, mA2, a3);
            lo = __builtin_amdgcn_cvt_pk_f32_fp8(uc3, false);
            hi = __builtin_amdgcn_cvt_pk_f32_fp8(uc3, true);
            a0 = fmaf(lo.x, mA3, a0); a1 = fmaf(lo.y, mA3, a1);
            a2 = fmaf(hi.x, mA3, a2); a3 = fmaf(hi.y, mA3, a3);
            cA0 = cB0; cA1 = cB1; cA2 = cB2; cA3 = cB3;
            cB0 = cC0; cB1 = cC1; cB2 = cC2; cB3 = cC3;
            uc0 = un0; uc1 = un1; uc2 = un2; uc3 = un3;
        }
        a0 += __shfl_xor(a0, 32);
        a1 += __shfl_xor(a1, 32);
        a2 += __shfl_xor(a2, 32);
        a3 += __shfl_xor(a3, 32);
        uint_t us = HC[(size_t)n * 32 + hoff];
        floatx2 slo = __builtin_amdgcn_cvt_pk_f32_fp8(us, false);
        floatx2 shi = __builtin_amdgcn_cvt_pk_f32_fp8(us, true);
        float v0 = fmaf(slo.x, w2, a0) + b4.x;
        float v1 = fmaf(slo.y, w2, a1) + b4.y;
        float v2 = fmaf(shi.x, w2, a2) + b4.z;
        float v3 = fmaf(shi.y, w2, a3) + b4.w;
        v0 = v0 > 0.f ? v0 : v0 * a4.x;
        v1 = v1 > 0.f ? v1 : v1 * a4.y;
        v2 = v2 > 0.f ? v2 : v2 * a4.z;
        v3 = v3 > 0.f ? v3 : v3 * a4.w;
        if (lane < 32) {
            uint_t pk = 0;
            pk = __builtin_amdgcn_cvt_pk_fp8_f32(v0, v1, pk, false);
            pk = __builtin_amdgcn_cvt_pk_fp8_f32(v2, v3, pk, true);
            uint_t* outp = isneg ? negq : posq;
            outp[(size_t)n * 16 + sub] = pk;
            if (!isneg) { s0 += v0; s1 += v1; s2 += v2; s3 += v3; }
        }
    }

    __shared__ float red[4][64];
    int w = tid >> 6;
    if (slot == 0) {
        red[w][sub * 4 + 0] = s0;
        red[w][sub * 4 + 1] = s1;
        red[w][sub * 4 + 2] = s2;
        red[w][sub * 4 + 3] = s3;
    }
    __syncthreads();
    if (tid < 64) {
        float s = red[0][tid] + red[1][tid] + red[2][tid] + red[3][tid];
        atomicAdd(&sumvec[tid], s);
    }
}

// ===== K5: loss — fp8 pos/neg, 2 nodes/wave-iter, disc fused, final ========
__global__ __launch_bounds__(256) void k_loss(const uint_t* __restrict__ posq,
                                              const uint_t* __restrict__ negq,
                                              float* __restrict__ smallb,
                                              const float* __restrict__ Wd,
                                              float* __restrict__ out, int N) {
    __shared__ float summ[64];
    __shared__ float svecS[64];
    __shared__ float redL[4][4];
    int tid = threadIdx.x;
    float* sumvec = smallb;
    float* lossAcc = smallb + 128;
    int* done = (int*)(smallb + 129);

    if (tid < 64) summ[tid] = 1.f / (1.f + expf(-sumvec[tid] / (float)N));
    __syncthreads();
    if (tid < 64) {
        float s = 0.f;
#pragma unroll
        for (int j = 0; j < 64; j++) s += Wd[tid * 64 + j] * summ[j];
        svecS[tid] = s;
    }
    __syncthreads();

    int lane = tid & 63;
    int slot = lane >> 4;
    int sub = lane & 15;
    int isneg = slot & 1;
    int pair = slot >> 1;
    int w = tid >> 6;
    float4 sv = ((const float4*)svecS)[sub];
    const uint_t* Pb = isneg ? negq : posq;
    float l = 0.f;
    int wid = (blockIdx.x * 256 + tid) >> 6;
    int nw = gridDim.x * 4;
    for (int g = wid; 2 * g < N; g += nw) {
        int row = 2 * g + pair;
        bool valid = row < N;
        uint_t u = valid ? Pb[(size_t)row * 16 + sub] : 0u;
        floatx2 lo = __builtin_amdgcn_cvt_pk_f32_fp8(u, false);
        floatx2 hi = __builtin_amdgcn_cvt_pk_f32_fp8(u, true);
        float p = lo.x * sv.x + lo.y * sv.y + hi.x * sv.z + hi.y * sv.w;
        p += __shfl_xor(p, 1);
        p += __shfl_xor(p, 2);
        p += __shfl_xor(p, 4);
        p += __shfl_xor(p, 8);
        if (sub == 0 && valid) l += isneg ? softplusf(p) : softplusf(-p);
    }
    if (sub == 0) redL[w][slot] = l;
    __syncthreads();
    if (tid == 0) {
        float t = 0.f;
#pragma unroll
        for (int i = 0; i < 4; i++)
#pragma unroll
            for (int j = 0; j < 4; j++) t += redL[i][j];
        atomicAdd(&lossAcc[0], t);
        __threadfence();
        int old = atomicAdd(done, 1);
        if (old == (int)gridDim.x - 1) {
            float tot = atomicAdd(&lossAcc[0], 0.f);
            out[0] = tot / (float)N;
        }
    }
}

extern "C" void kernel_launch(void* const* d_in, const int* in_sizes, int n_in,
                              void* d_out, int out_size, void* d_ws, size_t ws_size,
                              hipStream_t stream) {
    const float* x      = (const float*)d_in[0];
    const float* W_gcn  = (const float*)d_in[1];
    const float* b_gcn  = (const float*)d_in[2];
    const float* prelu_a= (const float*)d_in[3];
    const float* W_disc = (const float*)d_in[4];
    const int*   eidx   = (const int*)d_in[5];
    const int*   perm   = (const int*)d_in[6];

    int N = in_sizes[0] / INDIM;      // 100000
    int E = in_sizes[5] / 2;          // 1600000
    const int* src = eidx;
    const int* dst = eidx + E;

    char* base = (char*)d_ws;
    size_t off = 0;
    auto alloc = [&](size_t bytes) { size_t o = off; off = (off + bytes + 255) & ~(size_t)255; return o; };
    uint_t*   Hq    = (uint_t*)  (base + alloc((size_t)N * HID));              // fp8: 6.4 MB
    uint_t*   HC    = (uint_t*)  (base + alloc(((size_t)0x20000 * 32) * 4));   // 16.8 MB
    uint_t*   posq  = (uint_t*)  (base + alloc((size_t)N * HID));              // fp8
    uint_t*   negq  = (uint_t*)  (base + alloc((size_t)N * HID));              // fp8
    uint_t*   csrS  = (uint_t*)  (base + alloc(((size_t)NBUCK * PAD_PER + 64) * 4));
    int2*     ebuf  = (int2*)   (base + alloc((size_t)NBUCK * EBUF_PER * 8));
    int*      rowptr= (int*)    (base + alloc(((size_t)N + 1) * 4));
    float*    dinv  = (float*)  (base + alloc((size_t)N * 4));
    size_t zOff = alloc(NBUCK * 4 + 132 * 4);
    int*      bcur  = (int*)(base + zOff);
    float*    smallb= (float*)(base + zOff + NBUCK * 4);
    float* sumvec = smallb;

    int nbA = (E + CHUNK - 1) / CHUNK;    // 391
    int nbG = (N + 63) / 64;              // 1563
    int nbB = (N + 511) / 512;            // 196
    int nbH = (N * 16 + 255) / 256;       // 6250

    hipMemsetAsync(bcur, 0, NBUCK * 4 + 132 * 4, stream);
    k_fused<<<nbA + nbG, 256, 0, stream>>>(x, W_gcn, src, dst, Hq, bcur, ebuf, N, E, nbA);
    k_binB1hc<<<nbB + nbH, 256, 0, stream>>>(ebuf, bcur, rowptr, dinv, Hq, perm, HC, N, nbB);
    k_binB2<<<nbB, 256, 0, stream>>>(ebuf, bcur, rowptr, dinv, csrS, N);
    k_gather<<<2048, 256, 0, stream>>>(HC, rowptr, csrS, dinv,
                                       b_gcn, prelu_a, posq, negq, sumvec, N);
    k_loss<<<512, 256, 0, stream>>>(posq, negq, smallb, W_disc, (float*)d_out, N);
}